// Round 5
// baseline (407.790 us; speedup 1.0000x reference)
//
#include <hip/hip_runtime.h>
#include <hip/hip_cooperative_groups.h>
#include <math.h>

namespace cg = cooperative_groups;

// Problem constants (MultiHeadCRA): B=8, C=1024, H=W=64
#define SDIM 4096      // spatial S = H*W
#define DDIM 128       // head_dim
#define RED 8          // reduced dim
#define BATCH 8
#define BH 64          // BATCH*HEADS
#define CH 1024        // channels per batch = HEADS*DDIM

#define NBLK 256       // cooperative grid: 1 block/CU — runtime cannot reject
#define NTHR 512       // 8 waves/block

// native 16B vector for nontemporal builtins (HIP float4 is a class type)
typedef float vfloat4 __attribute__((ext_vector_type(4)));

// unified workspace layout (floats):
//   avg    [8192]     @ 0        (b*1024 + h*128 + d)
//   wq_eff [BH*128]   @ 8192
//   vvec   [BH*128]   @ 16384
//   cconst [BH]       @ 24576
//   scores [BH*4096]  @ 32768    (attn in place)
#define WS_WQ  8192
#define WS_V   16384
#define WS_C   24576
#define WS_SC  32768

__inline__ __device__ float wave_reduce_sum(float v) {
#pragma unroll
    for (int o = 32; o > 0; o >>= 1) v += __shfl_down(v, o, 64);
    return v;
}
__inline__ __device__ float wave_reduce_max(float v) {
#pragma unroll
    for (int o = 32; o > 0; o >>= 1) v = fmaxf(v, __shfl_down(v, o, 64));
    return v;
}

// ============================ fused cooperative ============================
__global__ __launch_bounds__(NTHR, 2) void k_fused(
        const float* __restrict__ x,
        const float* __restrict__ Wq, const float* __restrict__ bq,
        const float* __restrict__ Wk, const float* __restrict__ bk,
        const float* __restrict__ Wv, const float* __restrict__ bv,
        float* __restrict__ out, float* __restrict__ ws) {
    cg::grid_group grid = cg::this_grid();
    const int blk = blockIdx.x;
    const int t = threadIdx.x;
    const int wave = t >> 6, lane = t & 63;

    // ---- P1: per-channel spatial mean. 32 rows/block, 4 rows/wave. ----
#pragma unroll
    for (int r = 0; r < 4; ++r) {
        const int row = blk * 32 + wave * 4 + r;        // 0..8191
        const float4* xr = (const float4*)(x + (size_t)row * SDIM);
        float s = 0.f;
#pragma unroll
        for (int p = 0; p < 16; ++p) {
            float4 v = xr[lane + 64 * p];
            s += (v.x + v.y) + (v.z + v.w);
        }
        s = wave_reduce_sum(s);
        if (lane == 0) ws[row] = s * (1.0f / SDIM);
    }
    grid.sync();

    __shared__ float avgs[DDIM];
    __shared__ float kk[RED];
    __shared__ float wqs[DDIM];
    __shared__ float cc;
    __shared__ float smax[8];
    __shared__ float ssum[8];

    // ---- P2: head math (k, wq_eff, v, score-const) on blocks 0..63 ----
    if (blk < BH) {
        const int b = blk >> 3, h = blk & 7;
        if (t < DDIM) avgs[t] = ws[b * CH + h * DDIM + t];
        __syncthreads();
        if (t < RED) {
            const float* wkr = Wk + (h * RED + t) * DDIM;
            float acc = 0.f;
#pragma unroll 8
            for (int d = 0; d < DDIM; ++d) acc += wkr[d] * avgs[d];
            kk[t] = acc + bk[h * RED + t];
        }
        __syncthreads();
        if (t < DDIM) {
            float acc = 0.f;
#pragma unroll
            for (int r = 0; r < RED; ++r) acc += Wq[(h * RED + r) * DDIM + t] * kk[r];
            ws[WS_WQ + blk * DDIM + t] = acc;
            const float* wvr = Wv + (h * DDIM + t) * DDIM;
            float vacc = 0.f;
#pragma unroll 8
            for (int d = 0; d < DDIM; ++d) vacc += wvr[d] * avgs[d];
            ws[WS_V + blk * DDIM + t] = vacc + bv[h * DDIM + t];
        }
        if (t == 0) {
            float acc = 0.f;
#pragma unroll
            for (int r = 0; r < RED; ++r) acc += bq[h * RED + r] * kk[r];
            ws[WS_C + blk] = acc;
        }
    }
    grid.sync();

    // ---- P3: scores[bh,s] = sum_d x[bh*128+d, s]*wq_eff[d] + c.
    //      256 blocks = 64 bh x 4 s-chunks of 1024; 512 thr x float2. ----
    {
        const int bh = blk >> 2, chunk = blk & 3;
        const int b = bh >> 3, h = bh & 7;
        if (t < DDIM) wqs[t] = ws[WS_WQ + bh * DDIM + t];
        if (t == 0) cc = ws[WS_C + bh];
        __syncthreads();
        const int s0 = chunk * 1024 + t * 2;
        const float* xb = x + (size_t)(b * CH + h * DDIM) * SDIM + s0;
        const float c = cc;
        float2 acc; acc.x = c; acc.y = c;
#pragma unroll 16
        for (int d = 0; d < DDIM; ++d) {
            float2 xv = *(const float2*)(xb + (size_t)d * SDIM);
            const float w = wqs[d];
            acc.x += xv.x * w; acc.y += xv.y * w;
        }
        *(float2*)(ws + WS_SC + (size_t)bh * SDIM + s0) = acc;
    }
    grid.sync();

    // ---- P4: softmax over S in place, blocks 0..63. 512 thr x 8 floats. ----
    if (blk < BH) {
        float4* sc = (float4*)(ws + WS_SC + (size_t)blk * SDIM);
        float4 vals[2];
        float m = -1e30f;
#pragma unroll
        for (int p = 0; p < 2; ++p) {
            vals[p] = sc[t + NTHR * p];
            m = fmaxf(m, fmaxf(fmaxf(vals[p].x, vals[p].y), fmaxf(vals[p].z, vals[p].w)));
        }
        m = wave_reduce_max(m);
        if (lane == 0) smax[wave] = m;
        __syncthreads();
        float gm = smax[0];
#pragma unroll
        for (int w2 = 1; w2 < 8; ++w2) gm = fmaxf(gm, smax[w2]);
        float sum = 0.f;
#pragma unroll
        for (int p = 0; p < 2; ++p) {
            vals[p].x = expf(vals[p].x - gm);
            vals[p].y = expf(vals[p].y - gm);
            vals[p].z = expf(vals[p].z - gm);
            vals[p].w = expf(vals[p].w - gm);
            sum += vals[p].x + vals[p].y + vals[p].z + vals[p].w;
        }
        sum = wave_reduce_sum(sum);
        if (lane == 0) ssum[wave] = sum;
        __syncthreads();
        float tot = ssum[0];
#pragma unroll
        for (int w2 = 1; w2 < 8; ++w2) tot += ssum[w2];
        const float inv = 1.0f / tot;
#pragma unroll
        for (int p = 0; p < 2; ++p) {
            float4 o;
            o.x = vals[p].x * inv; o.y = vals[p].y * inv;
            o.z = vals[p].z * inv; o.w = vals[p].w * inv;
            sc[t + NTHR * p] = o;
        }
    }
    grid.sync();

    // ---- P5: out[b, h*128+e, s] = attn[bh,s] * v[bh,e]. All blocks. ----
    {
        const vfloat4* attn = (const vfloat4*)(ws + WS_SC);
        const float* vv = ws + WS_V;
        const size_t total = (size_t)BATCH * CH * (SDIM / 4);   // 8388608
        const size_t stride = (size_t)NBLK * NTHR;              // 131072
        for (size_t f = (size_t)blk * NTHR + t; f < total; f += stride) {
            const int s4 = (int)(f & 1023);
            const int ce = (int)((f >> 10) & 1023);
            const int b = (int)(f >> 20);
            const int bh = (b << 3) | (ce >> 7);
            const int e = ce & 127;
            const vfloat4 a = attn[bh * 1024 + s4];
            const float vx = vv[bh * 128 + e];
            vfloat4 o = a * vx;
            __builtin_nontemporal_store(o, ((vfloat4*)out) + f);
        }
    }
}

// ===================== fallback: proven R3 4-kernel path =====================
__global__ __launch_bounds__(256) void k_avg(const float* __restrict__ x,
                                             float* __restrict__ ws) {
    const int row = blockIdx.x;
    const int t = threadIdx.x;
    const float4* xr = (const float4*)(x + (size_t)row * SDIM);
    float s = 0.f;
#pragma unroll
    for (int p = 0; p < 4; ++p) {
        float4 v = xr[t + 256 * p];
        s += v.x + v.y + v.z + v.w;
    }
    s = wave_reduce_sum(s);
    __shared__ float part[4];
    const int wave = t >> 6, lane = t & 63;
    if (lane == 0) part[wave] = s;
    __syncthreads();
    if (t == 0) ws[row] = (part[0] + part[1] + part[2] + part[3]) * (1.0f / SDIM);
}

__global__ __launch_bounds__(256) void k_scores(
        const float* __restrict__ x,
        const float* __restrict__ Wq, const float* __restrict__ bq,
        const float* __restrict__ Wk, const float* __restrict__ bk,
        float* __restrict__ ws) {
    const int blk = blockIdx.x;
    const int bh = blk >> 3, chunk = blk & 7;
    const int b = bh >> 3, h = bh & 7;
    const int t = threadIdx.x;
    __shared__ float avgs[DDIM];
    __shared__ float kk[RED];
    __shared__ float wqs[DDIM];
    __shared__ float cc;
    if (t < DDIM) avgs[t] = ws[b * CH + h * DDIM + t];
    __syncthreads();
    if (t < RED) {
        const float* wkr = Wk + (h * RED + t) * DDIM;
        float acc = 0.f;
#pragma unroll 8
        for (int d = 0; d < DDIM; ++d) acc += wkr[d] * avgs[d];
        kk[t] = acc + bk[h * RED + t];
    }
    __syncthreads();
    if (t < DDIM) {
        float acc = 0.f;
#pragma unroll
        for (int r = 0; r < RED; ++r) acc += Wq[(h * RED + r) * DDIM + t] * kk[r];
        wqs[t] = acc;
    }
    if (t == 0) {
        float acc = 0.f;
#pragma unroll
        for (int r = 0; r < RED; ++r) acc += bq[h * RED + r] * kk[r];
        cc = acc;
    }
    __syncthreads();
    const int s0 = chunk * 512 + t * 2;
    const float* xb = x + (size_t)(b * CH + h * DDIM) * SDIM + s0;
    float2 acc;
    const float c = cc;
    acc.x = c; acc.y = c;
#pragma unroll 16
    for (int d = 0; d < DDIM; ++d) {
        float2 xv = *(const float2*)(xb + (size_t)d * SDIM);
        const float w = wqs[d];
        acc.x += xv.x * w; acc.y += xv.y * w;
    }
    *(float2*)(ws + WS_SC + (size_t)bh * SDIM + s0) = acc;
}

__global__ __launch_bounds__(256) void k_softmax_v(
        const float* __restrict__ Wv, const float* __restrict__ bv,
        float* __restrict__ ws) {
    const int bh = blockIdx.x;
    const int b = bh >> 3, h = bh & 7;
    const int t = threadIdx.x;
    __shared__ float avgs[DDIM];
    if (t < DDIM) avgs[t] = ws[b * CH + h * DDIM + t];
    __syncthreads();
    if (t < DDIM) {
        const float* wvr = Wv + (h * DDIM + t) * DDIM;
        float acc = 0.f;
#pragma unroll 8
        for (int d = 0; d < DDIM; ++d) acc += wvr[d] * avgs[d];
        ws[WS_V + bh * DDIM + t] = acc + bv[h * DDIM + t];
    }
    float4* sc = (float4*)(ws + WS_SC + (size_t)bh * SDIM);
    float4 vals[4];
    float m = -1e30f;
#pragma unroll
    for (int p = 0; p < 4; ++p) {
        vals[p] = sc[t + 256 * p];
        m = fmaxf(m, fmaxf(fmaxf(vals[p].x, vals[p].y), fmaxf(vals[p].z, vals[p].w)));
    }
    m = wave_reduce_max(m);
    __shared__ float smax[4];
    __shared__ float ssum[4];
    const int wave = t >> 6, lane = t & 63;
    if (lane == 0) smax[wave] = m;
    __syncthreads();
    const float gm = fmaxf(fmaxf(smax[0], smax[1]), fmaxf(smax[2], smax[3]));
    float sum = 0.f;
#pragma unroll
    for (int p = 0; p < 4; ++p) {
        vals[p].x = expf(vals[p].x - gm);
        vals[p].y = expf(vals[p].y - gm);
        vals[p].z = expf(vals[p].z - gm);
        vals[p].w = expf(vals[p].w - gm);
        sum += vals[p].x + vals[p].y + vals[p].z + vals[p].w;
    }
    sum = wave_reduce_sum(sum);
    if (lane == 0) ssum[wave] = sum;
    __syncthreads();
    const float inv = 1.0f / (ssum[0] + ssum[1] + ssum[2] + ssum[3]);
#pragma unroll
    for (int p = 0; p < 4; ++p) {
        float4 o;
        o.x = vals[p].x * inv; o.y = vals[p].y * inv;
        o.z = vals[p].z * inv; o.w = vals[p].w * inv;
        sc[t + 256 * p] = o;
    }
}

__global__ __launch_bounds__(256) void k_out(const float* __restrict__ ws,
                                             float* __restrict__ out) {
    const vfloat4* attn = (const vfloat4*)(ws + WS_SC);
    const float* vv = ws + WS_V;
    const size_t total = (size_t)BATCH * CH * (SDIM / 4);
    const size_t stride = (size_t)gridDim.x * blockDim.x;
    for (size_t f = (size_t)blockIdx.x * blockDim.x + threadIdx.x; f < total; f += stride) {
        const int s4 = (int)(f & 1023);
        const int ce = (int)((f >> 10) & 1023);
        const int b = (int)(f >> 20);
        const int bh = (b << 3) | (ce >> 7);
        const int e = ce & 127;
        const vfloat4 a = attn[bh * 1024 + s4];
        const float vx = vv[bh * 128 + e];
        vfloat4 o = a * vx;
        __builtin_nontemporal_store(o, ((vfloat4*)out) + f);
    }
}

extern "C" void kernel_launch(void* const* d_in, const int* in_sizes, int n_in,
                              void* d_out, int out_size, void* d_ws, size_t ws_size,
                              hipStream_t stream) {
    const float* x  = (const float*)d_in[0];
    const float* Wq = (const float*)d_in[1];
    const float* bq = (const float*)d_in[2];
    const float* Wk = (const float*)d_in[3];
    const float* bk = (const float*)d_in[4];
    const float* Wv = (const float*)d_in[5];
    const float* bv = (const float*)d_in[6];
    float* out = (float*)d_out;
    float* ws  = (float*)d_ws;

    void* args[] = { (void*)&x, (void*)&Wq, (void*)&bq, (void*)&Wk, (void*)&bk,
                     (void*)&Wv, (void*)&bv, (void*)&out, (void*)&ws };
    hipError_t err = hipLaunchCooperativeKernel((const void*)k_fused, dim3(NBLK),
                                                dim3(NTHR), args, 0, stream);
    if (err != hipSuccess) {
        // deterministic fallback: proven R3 pipeline
        k_avg<<<8192, 256, 0, stream>>>(x, ws);
        k_scores<<<512, 256, 0, stream>>>(x, Wq, bq, Wk, bk, ws);
        k_softmax_v<<<BH, 256, 0, stream>>>(Wv, bv, ws);
        k_out<<<8192, 256, 0, stream>>>(ws, out);
    }
}